// Round 9
// baseline (399.805 us; speedup 1.0000x reference)
//
#include <hip/hip_runtime.h>
#include <math.h>

#define NTHREADS 256
typedef __attribute__((ext_vector_type(8))) short short8;
typedef __attribute__((ext_vector_type(4))) float f32x4;
typedef unsigned short ushort_t;

// ---- conv kernel LDS: two time-major activation buffers hT[row=t+4][ch],
// 212 rows x stride 40 bf16. B-frag = one ds_read_b128. 33,920 B -> 4 blocks/CU.
#define HA    0
#define HB    8480
#define HSTR  40
#define SMEM_HW 16960

// ws layout: 35 A-frags bf16 (512 hw each) at 0; F fp32 at byte 65536.
#define WSF_C1 0
#define WSF_C2 (10*512)
#define WSF_C3 (20*512)
#define WSF_C4 (30*512)
#define WS_F_BYTE_OFF 65536

__device__ __forceinline__ unsigned f2bf(float f) {
    unsigned u = __float_as_uint(f);
    return (u + 0x7FFFu + ((u >> 16) & 1u)) >> 16;
}

__device__ __forceinline__ float gelu_fast(float x) {
    float x2 = x * x;
    float u  = x * fmaf(0.044715f, x2, 1.0f);
    float e  = __builtin_amdgcn_exp2f(u * 2.3022082f);
    float r  = __builtin_amdgcn_rcpf(e + 1.0f);
    float th = fmaf(-2.0f, r, 1.0f);
    float hx = 0.5f * x;
    return fmaf(hx, th, hx);
}

__device__ __forceinline__ float gelu_exact(float v) {
    return 0.5f * v * (1.0f + erff(v * 0.70710678118654752f));
}

#define JROT(Spp, Sqq, Spq, Sxp, Sxq, Vp0, Vq0, Vp1, Vq1, Vp2, Vq2)          \
    if (fabsf(Spq) > 1e-18f) {                                               \
        float tau = (Sqq - Spp) / (2.0f * Spq);                              \
        float tj = copysignf(1.0f, tau) / (fabsf(tau) + sqrtf(1.0f + tau*tau)); \
        float cj = 1.0f / sqrtf(1.0f + tj*tj);                               \
        float sj = tj * cj;                                                  \
        Spp -= tj * Spq; Sqq += tj * Spq; Spq = 0.0f;                        \
        float tmp0 = Sxp; Sxp = cj*tmp0 - sj*Sxq; Sxq = sj*tmp0 + cj*Sxq;    \
        float tv;                                                            \
        tv = Vp0; Vp0 = cj*tv - sj*Vq0; Vq0 = sj*tv + cj*Vq0;                \
        tv = Vp1; Vp1 = cj*tv - sj*Vq1; Vq1 = sj*tv + cj*Vq1;                \
        tv = Vp2; Vp2 = cj*tv - sj*Vq2; Vq2 = sj*tv + cj*Vq2;                \
    }

// ---- prep: repack conv weights into MFMA A-frag lane order (bf16).
__global__ void prep_kernel(const float* __restrict__ cw1,
                            const float* __restrict__ cw2,
                            const float* __restrict__ cw3,
                            const float* __restrict__ cw4,
                            ushort_t* __restrict__ ws)
{
    const int fid = blockIdx.x;              // 0..34
    const int l = threadIdx.x >> 3, j = threadIdx.x & 7;
    const int lo = l & 15, q = l >> 4;
    const int k = q * 8 + j;                 // 0..31
    float v = 0.0f;
    if (fid < 10) {                          // conv1: K=32, only i<6 real
        int tap = fid >> 1, Mt = fid & 1, c = Mt * 16 + lo;
        if (k < 6) v = cw1[(c * 6 + k) * 5 + tap];
    } else if (fid < 20) {                   // conv2
        int f = fid - 10, tap = f >> 1, Mt = f & 1, c = Mt * 16 + lo;
        v = cw2[(c * 32 + k) * 5 + tap];
    } else if (fid < 30) {                   // conv3
        int f = fid - 20, tap = f >> 1, Mt = f & 1, c = Mt * 16 + lo;
        v = cw3[(c * 32 + k) * 5 + tap];
    } else {                                 // conv4: row 0 only
        int tap = fid - 30;
        if (lo == 0) v = cw4[k * 5 + tap];
    }
    ws[fid * 512 + l * 8 + j] = (ushort_t)f2bf(v);
}

// ---- process 1 or 2 conv tiles (tile t0 and t0+4) interleaved for ILP ----
template<int DIL, bool TWO>
__device__ __forceinline__ void conv_tiles(
    const ushort_t* __restrict__ src, ushort_t* __restrict__ dst,
    const short8 A[5][2], f32x4 b0, f32x4 b1, int Lout,
    int lo16, int quad, int t0)
{
    f32x4 acc00 = b0, acc01 = b1, acc10 = b0, acc11 = b1;
    const int n0a = t0 * 16, n0b = (t0 + 4) * 16;
    #pragma unroll
    for (int t = 0; t < 5; t++) {
        int ra = n0a + lo16 + DIL * t; if (DIL == 3) ra = min(ra, 211);
        short8 Ba = *(const short8*)(src + ra * HSTR + quad * 8);
        acc00 = __builtin_amdgcn_mfma_f32_16x16x32_bf16(A[t][0], Ba, acc00, 0, 0, 0);
        acc01 = __builtin_amdgcn_mfma_f32_16x16x32_bf16(A[t][1], Ba, acc01, 0, 0, 0);
        if (TWO) {
            int rb = n0b + lo16 + DIL * t; if (DIL == 3) rb = min(rb, 211);
            short8 Bb = *(const short8*)(src + rb * HSTR + quad * 8);
            acc10 = __builtin_amdgcn_mfma_f32_16x16x32_bf16(A[t][0], Bb, acc10, 0, 0, 0);
            acc11 = __builtin_amdgcn_mfma_f32_16x16x32_bf16(A[t][1], Bb, acc11, 0, 0, 0);
        }
    }
    {
        const int n = n0a + lo16;
        unsigned p00 = 0, p01 = 0, p10 = 0, p11 = 0;
        if (n < Lout) {
            p00 = f2bf(gelu_fast(acc00[0])) | (f2bf(gelu_fast(acc00[1])) << 16);
            p01 = f2bf(gelu_fast(acc00[2])) | (f2bf(gelu_fast(acc00[3])) << 16);
            p10 = f2bf(gelu_fast(acc01[0])) | (f2bf(gelu_fast(acc01[1])) << 16);
            p11 = f2bf(gelu_fast(acc01[2])) | (f2bf(gelu_fast(acc01[3])) << 16);
        }
        ushort_t* row = dst + (4 + n) * HSTR;
        *(uint2*)(row + quad * 4)      = make_uint2(p00, p01);
        *(uint2*)(row + 16 + quad * 4) = make_uint2(p10, p11);
    }
    if (TWO) {
        const int n = n0b + lo16;
        unsigned p00 = 0, p01 = 0, p10 = 0, p11 = 0;
        if (n < Lout) {
            p00 = f2bf(gelu_fast(acc10[0])) | (f2bf(gelu_fast(acc10[1])) << 16);
            p01 = f2bf(gelu_fast(acc10[2])) | (f2bf(gelu_fast(acc10[3])) << 16);
            p10 = f2bf(gelu_fast(acc11[0])) | (f2bf(gelu_fast(acc11[1])) << 16);
            p11 = f2bf(gelu_fast(acc11[2])) | (f2bf(gelu_fast(acc11[3])) << 16);
        }
        ushort_t* row = dst + (4 + n) * HSTR;
        *(uint2*)(row + quad * 4)      = make_uint2(p00, p01);
        *(uint2*)(row + 16 + quad * 4) = make_uint2(p10, p11);
    }
}

// 13 tiles over 4 waves: wave0 {0,4,8,12}, wave w {w, w+4, w+8}
template<int DIL>
__device__ __forceinline__ void conv_mfma(
    const ushort_t* __restrict__ src, ushort_t* __restrict__ dst,
    const ushort_t* __restrict__ wsf, const float* __restrict__ bias,
    int Lout, int lane, int wave)
{
    const int lo16 = lane & 15, quad = lane >> 4;
    short8 A[5][2];
    #pragma unroll
    for (int t = 0; t < 5; t++) {
        A[t][0] = *(const short8*)(wsf + (t * 2 + 0) * 512 + lane * 8);
        A[t][1] = *(const short8*)(wsf + (t * 2 + 1) * 512 + lane * 8);
    }
    f32x4 b0, b1;
    #pragma unroll
    for (int r = 0; r < 4; r++) { b0[r] = bias[quad * 4 + r]; b1[r] = bias[16 + quad * 4 + r]; }
    conv_tiles<DIL, true>(src, dst, A, b0, b1, Lout, lo16, quad, wave);
    if (wave == 0) conv_tiles<DIL, true>(src, dst, A, b0, b1, Lout, lo16, quad, 8);
    else           conv_tiles<DIL, false>(src, dst, A, b0, b1, Lout, lo16, quad, wave + 8);
}

__global__ void __launch_bounds__(NTHREADS, 4)
rminet_conv_kernel(const float* __restrict__ x,
                   const float* __restrict__ calib,
                   const float* __restrict__ biasv,
                   const float* __restrict__ cb1, const float* __restrict__ cb2,
                   const float* __restrict__ cb3, const float* __restrict__ cb4,
                   const ushort_t* __restrict__ wsp,
                   float* __restrict__ F)
{
    __shared__ __align__(16) ushort_t smh[SMEM_HW];
    const int tid  = threadIdx.x;
    const int b    = blockIdx.x;
    const int lane = tid & 63;
    const int wave = __builtin_amdgcn_readfirstlane(tid >> 6);

    // Zero: bufA pad rows 0..3 (uint4 0..19), bufA rows 200..211 (uint4
    // 1000..1059 — rows 208..211 are read by conv2 as h1 idx 204..207 and are
    // NEVER written by any stage: they must be zero, not CU residue. R8's
    // replay-only divergence came from residue here), and ALL of bufB
    // (uint4 1060..2119). MFMA 0*NaN = NaN, so every readable byte must init.
    {
        uint4* p = (uint4*)smh;
        for (int i = tid; i < 1140; i += NTHREADS) {
            int idx = (i < 20) ? i : ((i < 80) ? 1000 + (i - 20) : 1060 + (i - 80));
            p[idx] = make_uint4(0u, 0u, 0u, 0u);
        }
    }
    __syncthreads();

    // calibrate + normalize -> bf16 xn rows [4+t][0..5] in bufB
    if (tid < 200) {
        const float* xc = x + (size_t)b * 1400 + 200 + tid;
        float v[6];
        #pragma unroll
        for (int ch = 0; ch < 6; ch++) v[ch] = xc[ch * 200];
        const float MEANS[6]  = {0.042766f, 0.0081577f, -0.015818f, 9.2993f, -0.087913f, -3.3231f};
        const float INVSTD[6] = {1.f/0.4142f, 1.f/0.3522f, 1.f/0.2881f, 1.f/1.474f, 1.f/0.6553f, 1.f/0.8728f};
        unsigned hv[6];
        #pragma unroll
        for (int i = 0; i < 6; i++) {
            float acc = biasv[i];
            #pragma unroll
            for (int jj = 0; jj < 6; jj++) {
                float m = calib[i * 6 + jj] + ((i == jj) ? 1.0f : 0.0f);
                acc = fmaf(m, v[jj], acc);
            }
            hv[i] = f2bf((acc - MEANS[i]) * INVSTD[i]);
        }
        ushort_t* row = smh + HB + (4 + tid) * HSTR;
        *(uint2*)row = make_uint2(hv[0] | (hv[1] << 16), hv[2] | (hv[3] << 16));
        *(unsigned*)(row + 4) = hv[4] | (hv[5] << 16);
    }
    __syncthreads();

    conv_mfma<1>(smh + HB, smh + HA, wsp + WSF_C1, cb1, 204, lane, wave);
    __syncthreads();
    conv_mfma<3>(smh + HA, smh + HB, wsp + WSF_C2, cb2, 200, lane, wave);
    __syncthreads();
    conv_mfma<3>(smh + HB, smh + HA, wsp + WSF_C3, cb3, 196, lane, wave);
    // Re-zero bufA rows 200..203 (uint4 1000..1019): they hold STALE h1 data
    // (conv1 wrote rows 4..207; conv3 only rewrote 4..199) but conv4 reads
    // them as h3 idx 196..199 which must be zero. Disjoint from conv3's
    // writes (rows <= 199), so safe before the same barrier.
    if (tid < 20) ((uint4*)smh)[1000 + tid] = make_uint4(0u, 0u, 0u, 0u);
    __syncthreads();

    // conv4 (MFMA, M-row 0 only): h3 -> F[b][192]
    {
        const int lo16 = lane & 15, quad = lane >> 4;
        short8 A4[5];
        #pragma unroll
        for (int t = 0; t < 5; t++)
            A4[t] = *(const short8*)(wsp + WSF_C4 + t * 512 + lane * 8);
        f32x4 acc[3];
        #pragma unroll
        for (int u = 0; u < 3; u++) acc[u] = (f32x4){0.f, 0.f, 0.f, 0.f};
        #pragma unroll
        for (int t = 0; t < 5; t++) {
            #pragma unroll
            for (int u = 0; u < 3; u++) {
                int r = (wave + 4 * u) * 16 + lo16 + 3 * t;   // <= 203
                short8 B = *(const short8*)(smh + HA + r * HSTR + quad * 8);
                acc[u] = __builtin_amdgcn_mfma_f32_16x16x32_bf16(A4[t], B, acc[u], 0, 0, 0);
            }
        }
        if (quad == 0) {
            const float c4 = cb4[0];
            #pragma unroll
            for (int u = 0; u < 3; u++) {
                int n = (wave + 4 * u) * 16 + lo16;
                F[(size_t)b * 192 + n] = gelu_fast(acc[u][0] + c4);
            }
        }
    }
}

// ---- tail v4: 8 items/block -> 1024 blocks (4/CU). Single wave per block,
// register-only compute (R6's proven tail), one barrier, no LDS reuse, no
// cross-wave hazards. Lanes >= 8 recompute item 7 (clamped) and store nothing.
__global__ void __launch_bounds__(64)
rminet_tail_kernel(const float* __restrict__ F,
                   const float* __restrict__ lw1, const float* __restrict__ lb1,
                   const float* __restrict__ lw2, const float* __restrict__ lb2,
                   const float* __restrict__ lw3, const float* __restrict__ lb3,
                   float* __restrict__ out)
{
    __shared__ __align__(16) float4 FT[48 * 9];   // 6,912 B
    const int t  = threadIdx.x;
    const int it = (t < 8) ? t : 7;               // clamped item index
    const int i0 = blockIdx.x * 8;

    // coalesced load of 8 items' f vectors (384 float4) + transpose into LDS
    {
        const float4* G4 = (const float4*)F + (size_t)i0 * 48;
        #pragma unroll
        for (int jj = 0; jj < 6; jj++) {
            int flat = jj * 64 + t;               // 0..383, each written once
            int item = flat / 48, k4 = flat - item * 48;
            FT[k4 * 9 + item] = G4[flat];
        }
    }
    __syncthreads();

    // linear1: 192 -> 50 (2 passes x 25 accumulators), gelu exact
    float z1[50];
    #pragma unroll
    for (int p = 0; p < 2; p++) {
        float acc[25];
        #pragma unroll
        for (int c = 0; c < 25; c++) acc[c] = lb1[p * 25 + c];
        #pragma unroll 4
        for (int j = 0; j < 48; j++) {
            float4 f = FT[j * 9 + it];
            #pragma unroll
            for (int c = 0; c < 25; c++) {
                const float4 w = *(const float4*)&lw1[(p * 25 + c) * 192 + j * 4];
                acc[c] = fmaf(w.x, f.x, fmaf(w.y, f.y, fmaf(w.z, f.z, fmaf(w.w, f.w, acc[c]))));
            }
        }
        #pragma unroll
        for (int c = 0; c < 25; c++) z1[p * 25 + c] = gelu_exact(acc[c]);
    }

    // linear2: 50 -> 50 (z1 in regs, wave-uniform weights -> s_load), gelu
    float z2[50];
    #pragma unroll
    for (int c = 0; c < 50; c++) {
        float a = lb2[c];
        #pragma unroll
        for (int k = 0; k < 50; k++) a = fmaf(lw2[c * 50 + k], z1[k], a);
        z2[c] = gelu_exact(a);
    }

    // linear3: 50 -> 15, *100
    float zv[15];
    #pragma unroll
    for (int c = 0; c < 15; c++) {
        float a = lb3[c];
        #pragma unroll
        for (int k = 0; k < 50; k++) a = fmaf(lw3[c * 50 + k], z2[k], a);
        zv[c] = a * 100.0f;
    }

    // stores + per-lane 3x3 SVD: only the 8 real items
    if (t < 8) {
        float* ob = out + (size_t)(i0 + t) * 15;
        #pragma unroll
        for (int c = 9; c < 15; c++) ob[c] = zv[c];

        const float A00 = zv[0], A01 = zv[1], A02 = zv[2];
        const float A10 = zv[3], A11 = zv[4], A12 = zv[5];
        const float A20 = zv[6], A21 = zv[7], A22 = zv[8];
        float S00 = A00*A00 + A10*A10 + A20*A20;
        float S01 = A00*A01 + A10*A11 + A20*A21;
        float S02 = A00*A02 + A10*A12 + A20*A22;
        float S11 = A01*A01 + A11*A11 + A21*A21;
        float S12 = A01*A02 + A11*A12 + A21*A22;
        float S22 = A02*A02 + A12*A12 + A22*A22;
        float V00=1.f, V01=0.f, V02=0.f;
        float V10=0.f, V11=1.f, V12=0.f;
        float V20=0.f, V21=0.f, V22=1.f;
        #pragma unroll
        for (int sweep = 0; sweep < 8; sweep++) {
            JROT(S00, S11, S01, S02, S12, V00, V01, V10, V11, V20, V21)
            JROT(S00, S22, S02, S01, S12, V00, V02, V10, V12, V20, V22)
            JROT(S11, S22, S12, S01, S02, V01, V02, V11, V12, V21, V22)
        }
        float e0 = S00, e1 = S11, e2 = S22;
        float va0=V00, va1=V10, va2=V20;
        float vb0=V01, vb1=V11, vb2=V21;
        float vc0=V02, vc1=V12, vc2=V22;
        float sgn = 1.0f, tq;
        if (e0 < e1) { tq=e0;e0=e1;e1=tq; tq=va0;va0=vb0;vb0=tq; tq=va1;va1=vb1;vb1=tq; tq=va2;va2=vb2;vb2=tq; sgn=-sgn; }
        if (e1 < e2) { tq=e1;e1=e2;e2=tq; tq=vb0;vb0=vc0;vc0=tq; tq=vb1;vb1=vc1;vc1=tq; tq=vb2;vb2=vc2;vc2=tq; sgn=-sgn; }
        if (e0 < e1) { tq=e0;e0=e1;e1=tq; tq=va0;va0=vb0;vb0=tq; tq=va1;va1=vb1;vb1=tq; tq=va2;va2=vb2;vb2=tq; sgn=-sgn; }
        vc0 *= sgn; vc1 *= sgn; vc2 *= sgn;
        float u10 = A00*va0 + A01*va1 + A02*va2;
        float u11 = A10*va0 + A11*va1 + A12*va2;
        float u12 = A20*va0 + A21*va1 + A22*va2;
        float n1 = sqrtf(u10*u10 + u11*u11 + u12*u12);
        float rn1 = (n1 > 1e-20f) ? 1.0f / n1 : 0.0f;
        u10 *= rn1; u11 *= rn1; u12 *= rn1;
        float u20 = A00*vb0 + A01*vb1 + A02*vb2;
        float u21 = A10*vb0 + A11*vb1 + A12*vb2;
        float u22 = A20*vb0 + A21*vb1 + A22*vb2;
        float d12 = u20*u10 + u21*u11 + u22*u12;
        u20 -= d12*u10; u21 -= d12*u11; u22 -= d12*u12;
        float n2 = sqrtf(u20*u20 + u21*u21 + u22*u22);
        float rn2 = (n2 > 1e-20f) ? 1.0f / n2 : 0.0f;
        u20 *= rn2; u21 *= rn2; u22 *= rn2;
        float u30 = u11*u22 - u12*u21;
        float u31 = u12*u20 - u10*u22;
        float u32 = u10*u21 - u11*u20;
        ob[0] = u10*va0 + u20*vb0 + u30*vc0;
        ob[1] = u10*va1 + u20*vb1 + u30*vc1;
        ob[2] = u10*va2 + u20*vb2 + u30*vc2;
        ob[3] = u11*va0 + u21*vb0 + u31*vc0;
        ob[4] = u11*va1 + u21*vb1 + u31*vc1;
        ob[5] = u11*va2 + u21*vb2 + u31*vc2;
        ob[6] = u12*va0 + u22*vb0 + u32*vc0;
        ob[7] = u12*va1 + u22*vb1 + u32*vc1;
        ob[8] = u12*va2 + u22*vb2 + u32*vc2;
    }
}

extern "C" void kernel_launch(void* const* d_in, const int* in_sizes, int n_in,
                              void* d_out, int out_size, void* d_ws, size_t ws_size,
                              hipStream_t stream) {
    (void)n_in; (void)out_size; (void)ws_size;
    const float* x     = (const float*)d_in[0];
    const float* calib = (const float*)d_in[1];
    const float* biasv = (const float*)d_in[2];
    const float* cw1   = (const float*)d_in[3];
    const float* cb1   = (const float*)d_in[4];
    const float* cw2   = (const float*)d_in[5];
    const float* cb2   = (const float*)d_in[6];
    const float* cw3   = (const float*)d_in[7];
    const float* cb3   = (const float*)d_in[8];
    const float* cw4   = (const float*)d_in[9];
    const float* cb4   = (const float*)d_in[10];
    const float* lw1   = (const float*)d_in[11];
    const float* lb1   = (const float*)d_in[12];
    const float* lw2   = (const float*)d_in[13];
    const float* lb2   = (const float*)d_in[14];
    const float* lw3   = (const float*)d_in[15];
    const float* lb3   = (const float*)d_in[16];
    float* out = (float*)d_out;
    ushort_t* wsh = (ushort_t*)d_ws;
    float* Fb = (float*)((char*)d_ws + WS_F_BYTE_OFF);
    const int B = in_sizes[0] / 1400;

    hipLaunchKernelGGL(prep_kernel, dim3(35), dim3(512), 0, stream,
                       cw1, cw2, cw3, cw4, wsh);
    hipLaunchKernelGGL(rminet_conv_kernel, dim3(B), dim3(NTHREADS), 0, stream,
                       x, calib, biasv, cb1, cb2, cb3, cb4,
                       (const ushort_t*)wsh, Fb);
    hipLaunchKernelGGL(rminet_tail_kernel, dim3(B / 8), dim3(64), 0, stream,
                       (const float*)Fb, lw1, lb1, lw2, lb2, lw3, lb3, out);
}

// Round 10
// 231.675 us; speedup vs baseline: 1.7257x; 1.7257x over previous
//
#include <hip/hip_runtime.h>
#include <math.h>

#define NTHREADS 256
typedef __attribute__((ext_vector_type(8))) short short8;
typedef __attribute__((ext_vector_type(4))) float f32x4;
typedef unsigned short ushort_t;

// ---- conv kernel LDS: two time-major activation buffers hT[row=t+4][ch],
// 212 rows x stride 40 bf16. B-frag = one ds_read_b128. 33,920 B -> 4 blocks/CU.
#define HA    0
#define HB    8480
#define HSTR  40
#define SMEM_HW 16960

// ws layout: 35 A-frags bf16 (512 hw each) at 0; F fp32 at byte 65536.
#define WSF_C1 0
#define WSF_C2 (10*512)
#define WSF_C3 (20*512)
#define WSF_C4 (30*512)
#define WS_F_BYTE_OFF 65536

__device__ __forceinline__ unsigned f2bf(float f) {
    unsigned u = __float_as_uint(f);
    return (u + 0x7FFFu + ((u >> 16) & 1u)) >> 16;
}

__device__ __forceinline__ float gelu_fast(float x) {
    float x2 = x * x;
    float u  = x * fmaf(0.044715f, x2, 1.0f);
    float e  = __builtin_amdgcn_exp2f(u * 2.3022082f);
    float r  = __builtin_amdgcn_rcpf(e + 1.0f);
    float th = fmaf(-2.0f, r, 1.0f);
    float hx = 0.5f * x;
    return fmaf(hx, th, hx);
}

__device__ __forceinline__ float gelu_exact(float v) {
    return 0.5f * v * (1.0f + erff(v * 0.70710678118654752f));
}

#define JROT(Spp, Sqq, Spq, Sxp, Sxq, Vp0, Vq0, Vp1, Vq1, Vp2, Vq2)          \
    if (fabsf(Spq) > 1e-18f) {                                               \
        float tau = (Sqq - Spp) / (2.0f * Spq);                              \
        float tj = copysignf(1.0f, tau) / (fabsf(tau) + sqrtf(1.0f + tau*tau)); \
        float cj = 1.0f / sqrtf(1.0f + tj*tj);                               \
        float sj = tj * cj;                                                  \
        Spp -= tj * Spq; Sqq += tj * Spq; Spq = 0.0f;                        \
        float tmp0 = Sxp; Sxp = cj*tmp0 - sj*Sxq; Sxq = sj*tmp0 + cj*Sxq;    \
        float tv;                                                            \
        tv = Vp0; Vp0 = cj*tv - sj*Vq0; Vq0 = sj*tv + cj*Vq0;                \
        tv = Vp1; Vp1 = cj*tv - sj*Vq1; Vq1 = sj*tv + cj*Vq1;                \
        tv = Vp2; Vp2 = cj*tv - sj*Vq2; Vq2 = sj*tv + cj*Vq2;                \
    }

// ---- prep: repack conv weights into MFMA A-frag lane order (bf16).
__global__ void prep_kernel(const float* __restrict__ cw1,
                            const float* __restrict__ cw2,
                            const float* __restrict__ cw3,
                            const float* __restrict__ cw4,
                            ushort_t* __restrict__ ws)
{
    const int fid = blockIdx.x;              // 0..34
    const int l = threadIdx.x >> 3, j = threadIdx.x & 7;
    const int lo = l & 15, q = l >> 4;
    const int k = q * 8 + j;                 // 0..31
    float v = 0.0f;
    if (fid < 10) {                          // conv1: K=32, only i<6 real
        int tap = fid >> 1, Mt = fid & 1, c = Mt * 16 + lo;
        if (k < 6) v = cw1[(c * 6 + k) * 5 + tap];
    } else if (fid < 20) {                   // conv2
        int f = fid - 10, tap = f >> 1, Mt = f & 1, c = Mt * 16 + lo;
        v = cw2[(c * 32 + k) * 5 + tap];
    } else if (fid < 30) {                   // conv3
        int f = fid - 20, tap = f >> 1, Mt = f & 1, c = Mt * 16 + lo;
        v = cw3[(c * 32 + k) * 5 + tap];
    } else {                                 // conv4: row 0 only
        int tap = fid - 30;
        if (lo == 0) v = cw4[k * 5 + tap];
    }
    ws[fid * 512 + l * 8 + j] = (ushort_t)f2bf(v);
}

// ---- process 1 or 2 conv tiles (tile t0 and t0+4) interleaved for ILP ----
template<int DIL, bool TWO>
__device__ __forceinline__ void conv_tiles(
    const ushort_t* __restrict__ src, ushort_t* __restrict__ dst,
    const short8 A[5][2], f32x4 b0, f32x4 b1, int Lout,
    int lo16, int quad, int t0)
{
    f32x4 acc00 = b0, acc01 = b1, acc10 = b0, acc11 = b1;
    const int n0a = t0 * 16, n0b = (t0 + 4) * 16;
    #pragma unroll
    for (int t = 0; t < 5; t++) {
        int ra = n0a + lo16 + DIL * t; if (DIL == 3) ra = min(ra, 211);
        short8 Ba = *(const short8*)(src + ra * HSTR + quad * 8);
        acc00 = __builtin_amdgcn_mfma_f32_16x16x32_bf16(A[t][0], Ba, acc00, 0, 0, 0);
        acc01 = __builtin_amdgcn_mfma_f32_16x16x32_bf16(A[t][1], Ba, acc01, 0, 0, 0);
        if (TWO) {
            int rb = n0b + lo16 + DIL * t; if (DIL == 3) rb = min(rb, 211);
            short8 Bb = *(const short8*)(src + rb * HSTR + quad * 8);
            acc10 = __builtin_amdgcn_mfma_f32_16x16x32_bf16(A[t][0], Bb, acc10, 0, 0, 0);
            acc11 = __builtin_amdgcn_mfma_f32_16x16x32_bf16(A[t][1], Bb, acc11, 0, 0, 0);
        }
    }
    {
        const int n = n0a + lo16;
        unsigned p00 = 0, p01 = 0, p10 = 0, p11 = 0;
        if (n < Lout) {
            p00 = f2bf(gelu_fast(acc00[0])) | (f2bf(gelu_fast(acc00[1])) << 16);
            p01 = f2bf(gelu_fast(acc00[2])) | (f2bf(gelu_fast(acc00[3])) << 16);
            p10 = f2bf(gelu_fast(acc01[0])) | (f2bf(gelu_fast(acc01[1])) << 16);
            p11 = f2bf(gelu_fast(acc01[2])) | (f2bf(gelu_fast(acc01[3])) << 16);
        }
        ushort_t* row = dst + (4 + n) * HSTR;
        *(uint2*)(row + quad * 4)      = make_uint2(p00, p01);
        *(uint2*)(row + 16 + quad * 4) = make_uint2(p10, p11);
    }
    if (TWO) {
        const int n = n0b + lo16;
        unsigned p00 = 0, p01 = 0, p10 = 0, p11 = 0;
        if (n < Lout) {
            p00 = f2bf(gelu_fast(acc10[0])) | (f2bf(gelu_fast(acc10[1])) << 16);
            p01 = f2bf(gelu_fast(acc10[2])) | (f2bf(gelu_fast(acc10[3])) << 16);
            p10 = f2bf(gelu_fast(acc11[0])) | (f2bf(gelu_fast(acc11[1])) << 16);
            p11 = f2bf(gelu_fast(acc11[2])) | (f2bf(gelu_fast(acc11[3])) << 16);
        }
        ushort_t* row = dst + (4 + n) * HSTR;
        *(uint2*)(row + quad * 4)      = make_uint2(p00, p01);
        *(uint2*)(row + 16 + quad * 4) = make_uint2(p10, p11);
    }
}

// 13 tiles over 4 waves: wave0 {0,4,8,12}, wave w {w, w+4, w+8}
template<int DIL>
__device__ __forceinline__ void conv_mfma(
    const ushort_t* __restrict__ src, ushort_t* __restrict__ dst,
    const ushort_t* __restrict__ wsf, const float* __restrict__ bias,
    int Lout, int lane, int wave)
{
    const int lo16 = lane & 15, quad = lane >> 4;
    short8 A[5][2];
    #pragma unroll
    for (int t = 0; t < 5; t++) {
        A[t][0] = *(const short8*)(wsf + (t * 2 + 0) * 512 + lane * 8);
        A[t][1] = *(const short8*)(wsf + (t * 2 + 1) * 512 + lane * 8);
    }
    f32x4 b0, b1;
    #pragma unroll
    for (int r = 0; r < 4; r++) { b0[r] = bias[quad * 4 + r]; b1[r] = bias[16 + quad * 4 + r]; }
    conv_tiles<DIL, true>(src, dst, A, b0, b1, Lout, lo16, quad, wave);
    if (wave == 0) conv_tiles<DIL, true>(src, dst, A, b0, b1, Lout, lo16, quad, 8);
    else           conv_tiles<DIL, false>(src, dst, A, b0, b1, Lout, lo16, quad, wave + 8);
}

__global__ void __launch_bounds__(NTHREADS, 4)
rminet_conv_kernel(const float* __restrict__ x,
                   const float* __restrict__ calib,
                   const float* __restrict__ biasv,
                   const float* __restrict__ cb1, const float* __restrict__ cb2,
                   const float* __restrict__ cb3, const float* __restrict__ cb4,
                   const ushort_t* __restrict__ wsp,
                   float* __restrict__ F)
{
    __shared__ __align__(16) ushort_t smh[SMEM_HW];
    const int tid  = threadIdx.x;
    const int b    = blockIdx.x;
    const int lane = tid & 63;
    const int wave = __builtin_amdgcn_readfirstlane(tid >> 6);

    // Zero: bufA pad rows 0..3 (uint4 0..19), bufA rows 200..211 (uint4
    // 1000..1059 — rows 208..211 are read by conv2 as h1 idx 204..207 and are
    // NEVER written by any stage: must be zero, not CU residue — R8's
    // replay-only divergence), and ALL of bufB (uint4 1060..2119).
    {
        uint4* p = (uint4*)smh;
        for (int i = tid; i < 1140; i += NTHREADS) {
            int idx = (i < 20) ? i : ((i < 80) ? 1000 + (i - 20) : 1060 + (i - 80));
            p[idx] = make_uint4(0u, 0u, 0u, 0u);
        }
    }
    __syncthreads();

    // calibrate + normalize -> bf16 xn rows [4+t][0..5] in bufB
    if (tid < 200) {
        const float* xc = x + (size_t)b * 1400 + 200 + tid;
        float v[6];
        #pragma unroll
        for (int ch = 0; ch < 6; ch++) v[ch] = xc[ch * 200];
        const float MEANS[6]  = {0.042766f, 0.0081577f, -0.015818f, 9.2993f, -0.087913f, -3.3231f};
        const float INVSTD[6] = {1.f/0.4142f, 1.f/0.3522f, 1.f/0.2881f, 1.f/1.474f, 1.f/0.6553f, 1.f/0.8728f};
        unsigned hv[6];
        #pragma unroll
        for (int i = 0; i < 6; i++) {
            float acc = biasv[i];
            #pragma unroll
            for (int jj = 0; jj < 6; jj++) {
                float m = calib[i * 6 + jj] + ((i == jj) ? 1.0f : 0.0f);
                acc = fmaf(m, v[jj], acc);
            }
            hv[i] = f2bf((acc - MEANS[i]) * INVSTD[i]);
        }
        ushort_t* row = smh + HB + (4 + tid) * HSTR;
        *(uint2*)row = make_uint2(hv[0] | (hv[1] << 16), hv[2] | (hv[3] << 16));
        *(unsigned*)(row + 4) = hv[4] | (hv[5] << 16);
    }
    __syncthreads();

    conv_mfma<1>(smh + HB, smh + HA, wsp + WSF_C1, cb1, 204, lane, wave);
    __syncthreads();
    conv_mfma<3>(smh + HA, smh + HB, wsp + WSF_C2, cb2, 200, lane, wave);
    __syncthreads();
    conv_mfma<3>(smh + HB, smh + HA, wsp + WSF_C3, cb3, 196, lane, wave);
    // Re-zero bufA rows 200..203: stale h1 data, but conv4 reads them as
    // h3 idx 196..199 which must be zero. Disjoint from conv3's writes.
    if (tid < 20) ((uint4*)smh)[1000 + tid] = make_uint4(0u, 0u, 0u, 0u);
    __syncthreads();

    // conv4 (MFMA, M-row 0 only): h3 -> F[b][192]
    {
        const int lo16 = lane & 15, quad = lane >> 4;
        short8 A4[5];
        #pragma unroll
        for (int t = 0; t < 5; t++)
            A4[t] = *(const short8*)(wsp + WSF_C4 + t * 512 + lane * 8);
        f32x4 acc[3];
        #pragma unroll
        for (int u = 0; u < 3; u++) acc[u] = (f32x4){0.f, 0.f, 0.f, 0.f};
        #pragma unroll
        for (int t = 0; t < 5; t++) {
            #pragma unroll
            for (int u = 0; u < 3; u++) {
                int r = (wave + 4 * u) * 16 + lo16 + 3 * t;   // <= 203
                short8 B = *(const short8*)(smh + HA + r * HSTR + quad * 8);
                acc[u] = __builtin_amdgcn_mfma_f32_16x16x32_bf16(A4[t], B, acc[u], 0, 0, 0);
            }
        }
        if (quad == 0) {
            const float c4 = cb4[0];
            #pragma unroll
            for (int u = 0; u < 3; u++) {
                int n = (wave + 4 * u) * 16 + lo16;
                F[(size_t)b * 192 + n] = gelu_fast(acc[u][0] + c4);
            }
        }
    }
}

// ---- tail v3 (re-validated): 16 items/block -> 512 blocks (2/CU, 8 waves/CU).
// lane = output channel (clamped), wave g = 4-item group (items wave-private
// => no barriers between linears). Weights staged in LDS float4; activations
// broadcast-read (wave-uniform address = free). R8's replay divergence was
// the conv kernel's unwritten rows 208..211, fixed in R9 — this tail's LDS
// map is fully covered by writes/zeroing.
#define TLW1 0
#define TLW2 2400
#define TLW3 3050
#define TFQ  3245
#define TZ1F 16052
#define TZVF 16884
#define TSM_FLOATS 17156

__global__ void __launch_bounds__(256)
rminet_tail_kernel(const float* __restrict__ F,
                   const float* __restrict__ lw1, const float* __restrict__ lb1,
                   const float* __restrict__ lw2, const float* __restrict__ lb2,
                   const float* __restrict__ lw3, const float* __restrict__ lb3,
                   float* __restrict__ out)
{
    __shared__ __align__(16) float smf[TSM_FLOATS];
    float4* smq = (float4*)smf;
    const int tid  = threadIdx.x;
    const int lane = tid & 63;
    const int g    = __builtin_amdgcn_readfirstlane(tid >> 6);
    const int i0   = blockIdx.x * 16;
    const int ib   = g * 4;                       // wave's 4 items

    // stage lw1 -> LW1[j4*50+c]
    for (int idx = tid; idx < 2400; idx += 256) {
        int j4 = idx / 50, c = idx - j4 * 50;
        smq[TLW1 + idx] = *(const float4*)&lw1[c * 192 + 4 * j4];
    }
    // stage lw2 (K padded 50->52 with zeros)
    for (int idx = tid; idx < 650; idx += 256) {
        int j4 = idx / 50, c = idx - j4 * 50;
        const float* wr = lw2 + c * 50 + 4 * j4;
        float4 w;
        w.x = wr[0]; w.y = wr[1];
        w.z = (4 * j4 + 2 < 50) ? wr[2] : 0.0f;
        w.w = (4 * j4 + 3 < 50) ? wr[3] : 0.0f;
        smq[TLW2 + idx] = w;
    }
    // stage lw3 (15 channels, K padded)
    for (int idx = tid; idx < 195; idx += 256) {
        int j4 = idx / 15, c = idx - j4 * 15;
        const float* wr = lw3 + c * 50 + 4 * j4;
        float4 w;
        w.x = wr[0]; w.y = wr[1];
        w.z = (4 * j4 + 2 < 50) ? wr[2] : 0.0f;
        w.w = (4 * j4 + 3 < 50) ? wr[3] : 0.0f;
        smq[TLW3 + idx] = w;
    }
    // stage F (16 items x 48 float4, contiguous -> coalesced)
    {
        const float4* G4 = (const float4*)F + (size_t)i0 * 48;
        for (int idx = tid; idx < 768; idx += 256) smq[TFQ + idx] = G4[idx];
    }
    // zero z1 K-pad [50..51] per item
    if (tid < 32) smf[TZ1F + (tid >> 1) * 52 + 50 + (tid & 1)] = 0.0f;
    __syncthreads();

    const int cc = min(lane, 49);

    // ---- linear1: 192 -> 50 ----
    {
        float a0, a1, a2, a3;
        a0 = a1 = a2 = a3 = lb1[cc];
        for (int j4 = 0; j4 < 48; j4++) {
            float4 w = smq[TLW1 + j4 * 50 + cc];
            float4 f0 = smq[TFQ + (ib + 0) * 48 + j4];
            float4 f1 = smq[TFQ + (ib + 1) * 48 + j4];
            float4 f2 = smq[TFQ + (ib + 2) * 48 + j4];
            float4 f3 = smq[TFQ + (ib + 3) * 48 + j4];
            a0 = fmaf(w.x, f0.x, fmaf(w.y, f0.y, fmaf(w.z, f0.z, fmaf(w.w, f0.w, a0))));
            a1 = fmaf(w.x, f1.x, fmaf(w.y, f1.y, fmaf(w.z, f1.z, fmaf(w.w, f1.w, a1))));
            a2 = fmaf(w.x, f2.x, fmaf(w.y, f2.y, fmaf(w.z, f2.z, fmaf(w.w, f2.w, a2))));
            a3 = fmaf(w.x, f3.x, fmaf(w.y, f3.y, fmaf(w.z, f3.z, fmaf(w.w, f3.w, a3))));
        }
        if (lane < 50) {
            smf[TZ1F + (ib + 0) * 52 + lane] = gelu_exact(a0);
            smf[TZ1F + (ib + 1) * 52 + lane] = gelu_exact(a1);
            smf[TZ1F + (ib + 2) * 52 + lane] = gelu_exact(a2);
            smf[TZ1F + (ib + 3) * 52 + lane] = gelu_exact(a3);
        }
    }
    // (items wave-private: wave program order suffices, no barrier)

    // ---- linear2: 50 -> 50 (in-place over z1; reads precede writes in
    // program order within the wave => safe) ----
    {
        float a0, a1, a2, a3;
        a0 = a1 = a2 = a3 = lb2[cc];
        for (int j4 = 0; j4 < 13; j4++) {
            float4 w = smq[TLW2 + j4 * 50 + cc];
            float4 z0 = *(const float4*)&smf[TZ1F + (ib + 0) * 52 + 4 * j4];
            float4 z1 = *(const float4*)&smf[TZ1F + (ib + 1) * 52 + 4 * j4];
            float4 z2 = *(const float4*)&smf[TZ1F + (ib + 2) * 52 + 4 * j4];
            float4 z3 = *(const float4*)&smf[TZ1F + (ib + 3) * 52 + 4 * j4];
            a0 = fmaf(w.x, z0.x, fmaf(w.y, z0.y, fmaf(w.z, z0.z, fmaf(w.w, z0.w, a0))));
            a1 = fmaf(w.x, z1.x, fmaf(w.y, z1.y, fmaf(w.z, z1.z, fmaf(w.w, z1.w, a1))));
            a2 = fmaf(w.x, z2.x, fmaf(w.y, z2.y, fmaf(w.z, z2.z, fmaf(w.w, z2.w, a2))));
            a3 = fmaf(w.x, z3.x, fmaf(w.y, z3.y, fmaf(w.z, z3.z, fmaf(w.w, z3.w, a3))));
        }
        if (lane < 50) {
            smf[TZ1F + (ib + 0) * 52 + lane] = gelu_exact(a0);
            smf[TZ1F + (ib + 1) * 52 + lane] = gelu_exact(a1);
            smf[TZ1F + (ib + 2) * 52 + lane] = gelu_exact(a2);
            smf[TZ1F + (ib + 3) * 52 + lane] = gelu_exact(a3);
        }
    }

    // ---- linear3: 50 -> 15, *100 -> ZV (stride 17) ----
    {
        const int c3 = min(lane, 14);
        float a0, a1, a2, a3;
        a0 = a1 = a2 = a3 = lb3[c3];
        for (int j4 = 0; j4 < 13; j4++) {
            float4 w = smq[TLW3 + j4 * 15 + c3];
            float4 z0 = *(const float4*)&smf[TZ1F + (ib + 0) * 52 + 4 * j4];
            float4 z1 = *(const float4*)&smf[TZ1F + (ib + 1) * 52 + 4 * j4];
            float4 z2 = *(const float4*)&smf[TZ1F + (ib + 2) * 52 + 4 * j4];
            float4 z3 = *(const float4*)&smf[TZ1F + (ib + 3) * 52 + 4 * j4];
            a0 = fmaf(w.x, z0.x, fmaf(w.y, z0.y, fmaf(w.z, z0.z, fmaf(w.w, z0.w, a0))));
            a1 = fmaf(w.x, z1.x, fmaf(w.y, z1.y, fmaf(w.z, z1.z, fmaf(w.w, z1.w, a1))));
            a2 = fmaf(w.x, z2.x, fmaf(w.y, z2.y, fmaf(w.z, z2.z, fmaf(w.w, z2.w, a2))));
            a3 = fmaf(w.x, z3.x, fmaf(w.y, z3.y, fmaf(w.z, z3.z, fmaf(w.w, z3.w, a3))));
        }
        if (lane < 15) {
            smf[TZVF + (ib + 0) * 17 + lane] = a0 * 100.0f;
            smf[TZVF + (ib + 1) * 17 + lane] = a1 * 100.0f;
            smf[TZVF + (ib + 2) * 17 + lane] = a2 * 100.0f;
            smf[TZVF + (ib + 3) * 17 + lane] = a3 * 100.0f;
        }
    }
    __syncthreads();

    // ---- wave 0, lanes 0..15: per-lane 3x3 SVD -> nearest rotation ----
    if (g == 0 && lane < 16) {
        const float* zv = &smf[TZVF + lane * 17];
        float* ob = out + (size_t)(i0 + lane) * 15;
        #pragma unroll
        for (int c = 9; c < 15; c++) ob[c] = zv[c];

        const float A00 = zv[0], A01 = zv[1], A02 = zv[2];
        const float A10 = zv[3], A11 = zv[4], A12 = zv[5];
        const float A20 = zv[6], A21 = zv[7], A22 = zv[8];
        float S00 = A00*A00 + A10*A10 + A20*A20;
        float S01 = A00*A01 + A10*A11 + A20*A21;
        float S02 = A00*A02 + A10*A12 + A20*A22;
        float S11 = A01*A01 + A11*A11 + A21*A21;
        float S12 = A01*A02 + A11*A12 + A21*A22;
        float S22 = A02*A02 + A12*A12 + A22*A22;
        float V00=1.f, V01=0.f, V02=0.f;
        float V10=0.f, V11=1.f, V12=0.f;
        float V20=0.f, V21=0.f, V22=1.f;
        #pragma unroll
        for (int sweep = 0; sweep < 8; sweep++) {
            JROT(S00, S11, S01, S02, S12, V00, V01, V10, V11, V20, V21)
            JROT(S00, S22, S02, S01, S12, V00, V02, V10, V12, V20, V22)
            JROT(S11, S22, S12, S01, S02, V01, V02, V11, V12, V21, V22)
        }
        float e0 = S00, e1 = S11, e2 = S22;
        float va0=V00, va1=V10, va2=V20;
        float vb0=V01, vb1=V11, vb2=V21;
        float vc0=V02, vc1=V12, vc2=V22;
        float sgn = 1.0f, tq;
        if (e0 < e1) { tq=e0;e0=e1;e1=tq; tq=va0;va0=vb0;vb0=tq; tq=va1;va1=vb1;vb1=tq; tq=va2;va2=vb2;vb2=tq; sgn=-sgn; }
        if (e1 < e2) { tq=e1;e1=e2;e2=tq; tq=vb0;vb0=vc0;vc0=tq; tq=vb1;vb1=vc1;vc1=tq; tq=vb2;vb2=vc2;vc2=tq; sgn=-sgn; }
        if (e0 < e1) { tq=e0;e0=e1;e1=tq; tq=va0;va0=vb0;vb0=tq; tq=va1;va1=vb1;vb1=tq; tq=va2;va2=vb2;vb2=tq; sgn=-sgn; }
        vc0 *= sgn; vc1 *= sgn; vc2 *= sgn;
        float u10 = A00*va0 + A01*va1 + A02*va2;
        float u11 = A10*va0 + A11*va1 + A12*va2;
        float u12 = A20*va0 + A21*va1 + A22*va2;
        float n1 = sqrtf(u10*u10 + u11*u11 + u12*u12);
        float rn1 = (n1 > 1e-20f) ? 1.0f / n1 : 0.0f;
        u10 *= rn1; u11 *= rn1; u12 *= rn1;
        float u20 = A00*vb0 + A01*vb1 + A02*vb2;
        float u21 = A10*vb0 + A11*vb1 + A12*vb2;
        float u22 = A20*vb0 + A21*vb1 + A22*vb2;
        float d12 = u20*u10 + u21*u11 + u22*u12;
        u20 -= d12*u10; u21 -= d12*u11; u22 -= d12*u12;
        float n2 = sqrtf(u20*u20 + u21*u21 + u22*u22);
        float rn2 = (n2 > 1e-20f) ? 1.0f / n2 : 0.0f;
        u20 *= rn2; u21 *= rn2; u22 *= rn2;
        float u30 = u11*u22 - u12*u21;
        float u31 = u12*u20 - u10*u22;
        float u32 = u10*u21 - u11*u20;
        ob[0] = u10*va0 + u20*vb0 + u30*vc0;
        ob[1] = u10*va1 + u20*vb1 + u30*vc1;
        ob[2] = u10*va2 + u20*vb2 + u30*vc2;
        ob[3] = u11*va0 + u21*vb0 + u31*vc0;
        ob[4] = u11*va1 + u21*vb1 + u31*vc1;
        ob[5] = u11*va2 + u21*vb2 + u31*vc2;
        ob[6] = u12*va0 + u22*vb0 + u32*vc0;
        ob[7] = u12*va1 + u22*vb1 + u32*vc1;
        ob[8] = u12*va2 + u22*vb2 + u32*vc2;
    }
}

extern "C" void kernel_launch(void* const* d_in, const int* in_sizes, int n_in,
                              void* d_out, int out_size, void* d_ws, size_t ws_size,
                              hipStream_t stream) {
    (void)n_in; (void)out_size; (void)ws_size;
    const float* x     = (const float*)d_in[0];
    const float* calib = (const float*)d_in[1];
    const float* biasv = (const float*)d_in[2];
    const float* cw1   = (const float*)d_in[3];
    const float* cb1   = (const float*)d_in[4];
    const float* cw2   = (const float*)d_in[5];
    const float* cb2   = (const float*)d_in[6];
    const float* cw3   = (const float*)d_in[7];
    const float* cb3   = (const float*)d_in[8];
    const float* cw4   = (const float*)d_in[9];
    const float* cb4   = (const float*)d_in[10];
    const float* lw1   = (const float*)d_in[11];
    const float* lb1   = (const float*)d_in[12];
    const float* lw2   = (const float*)d_in[13];
    const float* lb2   = (const float*)d_in[14];
    const float* lw3   = (const float*)d_in[15];
    const float* lb3   = (const float*)d_in[16];
    float* out = (float*)d_out;
    ushort_t* wsh = (ushort_t*)d_ws;
    float* Fb = (float*)((char*)d_ws + WS_F_BYTE_OFF);
    const int B = in_sizes[0] / 1400;

    hipLaunchKernelGGL(prep_kernel, dim3(35), dim3(512), 0, stream,
                       cw1, cw2, cw3, cw4, wsh);
    hipLaunchKernelGGL(rminet_conv_kernel, dim3(B), dim3(NTHREADS), 0, stream,
                       x, calib, biasv, cb1, cb2, cb3, cb4,
                       (const ushort_t*)wsh, Fb);
    hipLaunchKernelGGL(rminet_tail_kernel, dim3(B / 16), dim3(256), 0, stream,
                       (const float*)Fb, lw1, lb1, lw2, lb2, lw3, lb3, out);
}

// Round 11
// 214.497 us; speedup vs baseline: 1.8639x; 1.0801x over previous
//
#include <hip/hip_runtime.h>
#include <hip/hip_bf16.h>
#include <math.h>

#define NTHREADS 256
typedef __attribute__((ext_vector_type(8))) short short8;
typedef __attribute__((ext_vector_type(4))) float f32x4;
typedef unsigned short ushort_t;

// ---- conv kernel LDS: two time-major activation buffers hT[row=t+4][ch],
// 212 rows x stride 40 bf16. B-frag = one ds_read_b128. 33,920 B -> 4 blocks/CU.
#define HA    0
#define HB    8480
#define HSTR  40
#define SMEM_HW 16960

// ws layout: 35 A-frags bf16 (512 hw each) at 0; F fp32 at byte 65536.
#define WSF_C1 0
#define WSF_C2 (10*512)
#define WSF_C3 (20*512)
#define WSF_C4 (30*512)
#define WS_F_BYTE_OFF 65536

__device__ __forceinline__ unsigned f2bf(float f) {
    unsigned u = __float_as_uint(f);
    return (u + 0x7FFFu + ((u >> 16) & 1u)) >> 16;
}

// packed f32x2 -> bf16x2 RNE; on gfx950 lowers to v_cvt_pk_bf16_f32
// (1 instr vs ~10 for 2x shift-round+or); software fallback is equivalent.
__device__ __forceinline__ unsigned pack2bf(float a, float b) {
    __hip_bfloat162 h = __float22bfloat162_rn(make_float2(a, b));
    unsigned u; __builtin_memcpy(&u, &h, 4); return u;
}

// tanh-GELU, minimal-op form: gelu = x - x/(exp2(x*t)+1),
// t = 2*0.79788456*log2e * (1 + 0.044715 x^2). Same math as before, 2 fewer ops.
__device__ __forceinline__ float gelu_fast(float x) {
    float x2 = x * x;
    float t  = fmaf(0.10294320f, x2, 2.3022082f);
    float e  = __builtin_amdgcn_exp2f(x * t);
    float r  = __builtin_amdgcn_rcpf(e + 1.0f);
    return fmaf(-x, r, x);
}

__device__ __forceinline__ float gelu_exact(float v) {
    return 0.5f * v * (1.0f + erff(v * 0.70710678118654752f));
}

#define JROT(Spp, Sqq, Spq, Sxp, Sxq, Vp0, Vq0, Vp1, Vq1, Vp2, Vq2)          \
    if (fabsf(Spq) > 1e-18f) {                                               \
        float tau = (Sqq - Spp) / (2.0f * Spq);                              \
        float tj = copysignf(1.0f, tau) / (fabsf(tau) + sqrtf(1.0f + tau*tau)); \
        float cj = 1.0f / sqrtf(1.0f + tj*tj);                               \
        float sj = tj * cj;                                                  \
        Spp -= tj * Spq; Sqq += tj * Spq; Spq = 0.0f;                        \
        float tmp0 = Sxp; Sxp = cj*tmp0 - sj*Sxq; Sxq = sj*tmp0 + cj*Sxq;    \
        float tv;                                                            \
        tv = Vp0; Vp0 = cj*tv - sj*Vq0; Vq0 = sj*tv + cj*Vq0;                \
        tv = Vp1; Vp1 = cj*tv - sj*Vq1; Vq1 = sj*tv + cj*Vq1;                \
        tv = Vp2; Vp2 = cj*tv - sj*Vq2; Vq2 = sj*tv + cj*Vq2;                \
    }

// ---- prep: repack conv weights into MFMA A-frag lane order (bf16).
__global__ void prep_kernel(const float* __restrict__ cw1,
                            const float* __restrict__ cw2,
                            const float* __restrict__ cw3,
                            const float* __restrict__ cw4,
                            ushort_t* __restrict__ ws)
{
    const int fid = blockIdx.x;              // 0..34
    const int l = threadIdx.x >> 3, j = threadIdx.x & 7;
    const int lo = l & 15, q = l >> 4;
    const int k = q * 8 + j;                 // 0..31
    float v = 0.0f;
    if (fid < 10) {                          // conv1: K=32, only i<6 real
        int tap = fid >> 1, Mt = fid & 1, c = Mt * 16 + lo;
        if (k < 6) v = cw1[(c * 6 + k) * 5 + tap];
    } else if (fid < 20) {                   // conv2
        int f = fid - 10, tap = f >> 1, Mt = f & 1, c = Mt * 16 + lo;
        v = cw2[(c * 32 + k) * 5 + tap];
    } else if (fid < 30) {                   // conv3
        int f = fid - 20, tap = f >> 1, Mt = f & 1, c = Mt * 16 + lo;
        v = cw3[(c * 32 + k) * 5 + tap];
    } else {                                 // conv4: row 0 only
        int tap = fid - 30;
        if (lo == 0) v = cw4[k * 5 + tap];
    }
    ws[fid * 512 + l * 8 + j] = (ushort_t)f2bf(v);
}

// ---- process 1 or 2 conv tiles. Tile A (and non-edge tile B) use a single
// base pointer + constant tap offsets (fold into ds_read offset imm) and an
// unconditional epilogue: only tile 12 (EDGEB) ever needs the row clamp
// (dil=3) or the n<Lout store guard. Tile layout per conv_mfma: pairs (w,w+4)
// then wave0:(8,12-EDGE) / waves1-3:(w+8) — all non-edge tiles have
// n <= 191 < Lout(min 196) and max read row 191+12=203 <= 211.
template<int DIL, bool TWO, bool EDGEB>
__device__ __forceinline__ void conv_tiles(
    const ushort_t* __restrict__ src, ushort_t* __restrict__ dst,
    const short8 A[5][2], f32x4 b0, f32x4 b1, int Lout,
    int lo16, int quad, int t0)
{
    f32x4 acc00 = b0, acc01 = b1, acc10 = b0, acc11 = b1;
    const int n0a = t0 * 16, n0b = (t0 + 4) * 16;
    const ushort_t* pa = src + (n0a + lo16) * HSTR + quad * 8;
    const ushort_t* pb = src + (n0b + lo16) * HSTR + quad * 8;
    #pragma unroll
    for (int t = 0; t < 5; t++) {
        short8 Ba = *(const short8*)(pa + DIL * HSTR * t);
        acc00 = __builtin_amdgcn_mfma_f32_16x16x32_bf16(A[t][0], Ba, acc00, 0, 0, 0);
        acc01 = __builtin_amdgcn_mfma_f32_16x16x32_bf16(A[t][1], Ba, acc01, 0, 0, 0);
        if (TWO) {
            short8 Bb;
            if (EDGEB && DIL == 3) {
                int rb = min(n0b + lo16 + 3 * t, 211);   // clamp: garbage lanes discarded
                Bb = *(const short8*)(src + rb * HSTR + quad * 8);
            } else {
                Bb = *(const short8*)(pb + DIL * HSTR * t);
            }
            acc10 = __builtin_amdgcn_mfma_f32_16x16x32_bf16(A[t][0], Bb, acc10, 0, 0, 0);
            acc11 = __builtin_amdgcn_mfma_f32_16x16x32_bf16(A[t][1], Bb, acc11, 0, 0, 0);
        }
    }
    {   // tile A epilogue: never edge -> unconditional
        ushort_t* row = dst + (4 + n0a + lo16) * HSTR;
        *(uint2*)(row + quad * 4) = make_uint2(
            pack2bf(gelu_fast(acc00[0]), gelu_fast(acc00[1])),
            pack2bf(gelu_fast(acc00[2]), gelu_fast(acc00[3])));
        *(uint2*)(row + 16 + quad * 4) = make_uint2(
            pack2bf(gelu_fast(acc01[0]), gelu_fast(acc01[1])),
            pack2bf(gelu_fast(acc01[2]), gelu_fast(acc01[3])));
    }
    if (TWO) {
        const int n = n0b + lo16;
        ushort_t* row = dst + (4 + n) * HSTR;
        if (EDGEB) {
            unsigned p00 = 0, p01 = 0, p10 = 0, p11 = 0;
            if (n < Lout) {
                p00 = pack2bf(gelu_fast(acc10[0]), gelu_fast(acc10[1]));
                p01 = pack2bf(gelu_fast(acc10[2]), gelu_fast(acc10[3]));
                p10 = pack2bf(gelu_fast(acc11[0]), gelu_fast(acc11[1]));
                p11 = pack2bf(gelu_fast(acc11[2]), gelu_fast(acc11[3]));
            }
            // rows for n >= Lout get ZEROS: establishes next layer's tail pad.
            *(uint2*)(row + quad * 4)      = make_uint2(p00, p01);
            *(uint2*)(row + 16 + quad * 4) = make_uint2(p10, p11);
        } else {
            *(uint2*)(row + quad * 4) = make_uint2(
                pack2bf(gelu_fast(acc10[0]), gelu_fast(acc10[1])),
                pack2bf(gelu_fast(acc10[2]), gelu_fast(acc10[3])));
            *(uint2*)(row + 16 + quad * 4) = make_uint2(
                pack2bf(gelu_fast(acc11[0]), gelu_fast(acc11[1])),
                pack2bf(gelu_fast(acc11[2]), gelu_fast(acc11[3])));
        }
    }
}

// 13 tiles over 4 waves: wave0 {0,4,8,12(edge)}, wave w {w, w+4, w+8}
template<int DIL>
__device__ __forceinline__ void conv_mfma(
    const ushort_t* __restrict__ src, ushort_t* __restrict__ dst,
    const ushort_t* __restrict__ wsf, const float* __restrict__ bias,
    int Lout, int lane, int wave)
{
    const int lo16 = lane & 15, quad = lane >> 4;
    short8 A[5][2];
    #pragma unroll
    for (int t = 0; t < 5; t++) {
        A[t][0] = *(const short8*)(wsf + (t * 2 + 0) * 512 + lane * 8);
        A[t][1] = *(const short8*)(wsf + (t * 2 + 1) * 512 + lane * 8);
    }
    f32x4 b0, b1;
    #pragma unroll
    for (int r = 0; r < 4; r++) { b0[r] = bias[quad * 4 + r]; b1[r] = bias[16 + quad * 4 + r]; }
    conv_tiles<DIL, true, false>(src, dst, A, b0, b1, Lout, lo16, quad, wave);
    if (wave == 0) conv_tiles<DIL, true, true>(src, dst, A, b0, b1, Lout, lo16, quad, 8);
    else           conv_tiles<DIL, false, false>(src, dst, A, b0, b1, Lout, lo16, quad, wave + 8);
}

__global__ void __launch_bounds__(NTHREADS, 4)
rminet_conv_kernel(const float* __restrict__ x,
                   const float* __restrict__ calib,
                   const float* __restrict__ biasv,
                   const float* __restrict__ cb1, const float* __restrict__ cb2,
                   const float* __restrict__ cb3, const float* __restrict__ cb4,
                   const ushort_t* __restrict__ wsp,
                   float* __restrict__ F)
{
    __shared__ __align__(16) ushort_t smh[SMEM_HW];
    const int tid  = threadIdx.x;
    const int b    = blockIdx.x;
    const int lane = tid & 63;
    const int wave = __builtin_amdgcn_readfirstlane(tid >> 6);

    // Zero: bufA pad rows 0..3 (uint4 0..19), bufA rows 200..211 (uint4
    // 1000..1059 — replay-stability: proven necessary in R9/R10), and ALL of
    // bufB (uint4 1060..2119). MFMA 0*NaN = NaN; every readable byte inits.
    {
        uint4* p = (uint4*)smh;
        for (int i = tid; i < 1140; i += NTHREADS) {
            int idx = (i < 20) ? i : ((i < 80) ? 1000 + (i - 20) : 1060 + (i - 80));
            p[idx] = make_uint4(0u, 0u, 0u, 0u);
        }
    }
    __syncthreads();

    // calibrate + normalize -> bf16 xn rows [4+t][0..5] in bufB
    if (tid < 200) {
        const float* xc = x + (size_t)b * 1400 + 200 + tid;
        float v[6];
        #pragma unroll
        for (int ch = 0; ch < 6; ch++) v[ch] = xc[ch * 200];
        const float MEANS[6]  = {0.042766f, 0.0081577f, -0.015818f, 9.2993f, -0.087913f, -3.3231f};
        const float INVSTD[6] = {1.f/0.4142f, 1.f/0.3522f, 1.f/0.2881f, 1.f/1.474f, 1.f/0.6553f, 1.f/0.8728f};
        float xn[6];
        #pragma unroll
        for (int i = 0; i < 6; i++) {
            float acc = biasv[i];
            #pragma unroll
            for (int jj = 0; jj < 6; jj++) {
                float m = calib[i * 6 + jj] + ((i == jj) ? 1.0f : 0.0f);
                acc = fmaf(m, v[jj], acc);
            }
            xn[i] = (acc - MEANS[i]) * INVSTD[i];
        }
        ushort_t* row = smh + HB + (4 + tid) * HSTR;
        *(uint2*)row = make_uint2(pack2bf(xn[0], xn[1]), pack2bf(xn[2], xn[3]));
        *(unsigned*)(row + 4) = pack2bf(xn[4], xn[5]);
    }
    __syncthreads();

    conv_mfma<1>(smh + HB, smh + HA, wsp + WSF_C1, cb1, 204, lane, wave);
    __syncthreads();
    conv_mfma<3>(smh + HA, smh + HB, wsp + WSF_C2, cb2, 200, lane, wave);
    __syncthreads();
    conv_mfma<3>(smh + HB, smh + HA, wsp + WSF_C3, cb3, 196, lane, wave);
    // Re-zero bufA rows 200..203 before conv4 (stale-h1 guard; disjoint from
    // conv3's writes). Kept verbatim from R10 (replay-stability proven).
    if (tid < 20) ((uint4*)smh)[1000 + tid] = make_uint4(0u, 0u, 0u, 0u);
    __syncthreads();

    // conv4 (MFMA, M-row 0 only): h3 -> F[b][192]; base ptr + const tap offsets
    {
        const int lo16 = lane & 15, quad = lane >> 4;
        short8 A4[5];
        #pragma unroll
        for (int t = 0; t < 5; t++)
            A4[t] = *(const short8*)(wsp + WSF_C4 + t * 512 + lane * 8);
        f32x4 acc[3];
        #pragma unroll
        for (int u = 0; u < 3; u++) acc[u] = (f32x4){0.f, 0.f, 0.f, 0.f};
        const ushort_t* p4[3];
        #pragma unroll
        for (int u = 0; u < 3; u++)
            p4[u] = smh + HA + ((wave + 4 * u) * 16 + lo16) * HSTR + quad * 8;
        #pragma unroll
        for (int t = 0; t < 5; t++) {
            #pragma unroll
            for (int u = 0; u < 3; u++) {
                short8 B = *(const short8*)(p4[u] + 3 * HSTR * t);   // row <= 203
                acc[u] = __builtin_amdgcn_mfma_f32_16x16x32_bf16(A4[t], B, acc[u], 0, 0, 0);
            }
        }
        if (quad == 0) {
            const float c4 = cb4[0];
            #pragma unroll
            for (int u = 0; u < 3; u++) {
                int n = (wave + 4 * u) * 16 + lo16;
                F[(size_t)b * 192 + n] = gelu_fast(acc[u][0] + c4);
            }
        }
    }
}

// ---- tail v3 (unchanged from R10, replay-validated): 16 items/block ->
// 512 blocks (2/CU, 8 waves/CU). lane = output channel, wave g = 4-item group.
#define TLW1 0
#define TLW2 2400
#define TLW3 3050
#define TFQ  3245
#define TZ1F 16052
#define TZVF 16884
#define TSM_FLOATS 17156

__global__ void __launch_bounds__(256)
rminet_tail_kernel(const float* __restrict__ F,
                   const float* __restrict__ lw1, const float* __restrict__ lb1,
                   const float* __restrict__ lw2, const float* __restrict__ lb2,
                   const float* __restrict__ lw3, const float* __restrict__ lb3,
                   float* __restrict__ out)
{
    __shared__ __align__(16) float smf[TSM_FLOATS];
    float4* smq = (float4*)smf;
    const int tid  = threadIdx.x;
    const int lane = tid & 63;
    const int g    = __builtin_amdgcn_readfirstlane(tid >> 6);
    const int i0   = blockIdx.x * 16;
    const int ib   = g * 4;

    for (int idx = tid; idx < 2400; idx += 256) {
        int j4 = idx / 50, c = idx - j4 * 50;
        smq[TLW1 + idx] = *(const float4*)&lw1[c * 192 + 4 * j4];
    }
    for (int idx = tid; idx < 650; idx += 256) {
        int j4 = idx / 50, c = idx - j4 * 50;
        const float* wr = lw2 + c * 50 + 4 * j4;
        float4 w;
        w.x = wr[0]; w.y = wr[1];
        w.z = (4 * j4 + 2 < 50) ? wr[2] : 0.0f;
        w.w = (4 * j4 + 3 < 50) ? wr[3] : 0.0f;
        smq[TLW2 + idx] = w;
    }
    for (int idx = tid; idx < 195; idx += 256) {
        int j4 = idx / 15, c = idx - j4 * 15;
        const float* wr = lw3 + c * 50 + 4 * j4;
        float4 w;
        w.x = wr[0]; w.y = wr[1];
        w.z = (4 * j4 + 2 < 50) ? wr[2] : 0.0f;
        w.w = (4 * j4 + 3 < 50) ? wr[3] : 0.0f;
        smq[TLW3 + idx] = w;
    }
    {
        const float4* G4 = (const float4*)F + (size_t)i0 * 48;
        for (int idx = tid; idx < 768; idx += 256) smq[TFQ + idx] = G4[idx];
    }
    if (tid < 32) smf[TZ1F + (tid >> 1) * 52 + 50 + (tid & 1)] = 0.0f;
    __syncthreads();

    const int cc = min(lane, 49);

    {   // linear1: 192 -> 50
        float a0, a1, a2, a3;
        a0 = a1 = a2 = a3 = lb1[cc];
        for (int j4 = 0; j4 < 48; j4++) {
            float4 w = smq[TLW1 + j4 * 50 + cc];
            float4 f0 = smq[TFQ + (ib + 0) * 48 + j4];
            float4 f1 = smq[TFQ + (ib + 1) * 48 + j4];
            float4 f2 = smq[TFQ + (ib + 2) * 48 + j4];
            float4 f3 = smq[TFQ + (ib + 3) * 48 + j4];
            a0 = fmaf(w.x, f0.x, fmaf(w.y, f0.y, fmaf(w.z, f0.z, fmaf(w.w, f0.w, a0))));
            a1 = fmaf(w.x, f1.x, fmaf(w.y, f1.y, fmaf(w.z, f1.z, fmaf(w.w, f1.w, a1))));
            a2 = fmaf(w.x, f2.x, fmaf(w.y, f2.y, fmaf(w.z, f2.z, fmaf(w.w, f2.w, a2))));
            a3 = fmaf(w.x, f3.x, fmaf(w.y, f3.y, fmaf(w.z, f3.z, fmaf(w.w, f3.w, a3))));
        }
        if (lane < 50) {
            smf[TZ1F + (ib + 0) * 52 + lane] = gelu_exact(a0);
            smf[TZ1F + (ib + 1) * 52 + lane] = gelu_exact(a1);
            smf[TZ1F + (ib + 2) * 52 + lane] = gelu_exact(a2);
            smf[TZ1F + (ib + 3) * 52 + lane] = gelu_exact(a3);
        }
    }

    {   // linear2: 50 -> 50 (in-place; reads precede writes in wave order)
        float a0, a1, a2, a3;
        a0 = a1 = a2 = a3 = lb2[cc];
        for (int j4 = 0; j4 < 13; j4++) {
            float4 w = smq[TLW2 + j4 * 50 + cc];
            float4 z0 = *(const float4*)&smf[TZ1F + (ib + 0) * 52 + 4 * j4];
            float4 z1 = *(const float4*)&smf[TZ1F + (ib + 1) * 52 + 4 * j4];
            float4 z2 = *(const float4*)&smf[TZ1F + (ib + 2) * 52 + 4 * j4];
            float4 z3 = *(const float4*)&smf[TZ1F + (ib + 3) * 52 + 4 * j4];
            a0 = fmaf(w.x, z0.x, fmaf(w.y, z0.y, fmaf(w.z, z0.z, fmaf(w.w, z0.w, a0))));
            a1 = fmaf(w.x, z1.x, fmaf(w.y, z1.y, fmaf(w.z, z1.z, fmaf(w.w, z1.w, a1))));
            a2 = fmaf(w.x, z2.x, fmaf(w.y, z2.y, fmaf(w.z, z2.z, fmaf(w.w, z2.w, a2))));
            a3 = fmaf(w.x, z3.x, fmaf(w.y, z3.y, fmaf(w.z, z3.z, fmaf(w.w, z3.w, a3))));
        }
        if (lane < 50) {
            smf[TZ1F + (ib + 0) * 52 + lane] = gelu_exact(a0);
            smf[TZ1F + (ib + 1) * 52 + lane] = gelu_exact(a1);
            smf[TZ1F + (ib + 2) * 52 + lane] = gelu_exact(a2);
            smf[TZ1F + (ib + 3) * 52 + lane] = gelu_exact(a3);
        }
    }

    {   // linear3: 50 -> 15, *100 -> ZV (stride 17)
        const int c3 = min(lane, 14);
        float a0, a1, a2, a3;
        a0 = a1 = a2 = a3 = lb3[c3];
        for (int j4 = 0; j4 < 13; j4++) {
            float4 w = smq[TLW3 + j4 * 15 + c3];
            float4 z0 = *(const float4*)&smf[TZ1F + (ib + 0) * 52 + 4 * j4];
            float4 z1 = *(const float4*)&smf[TZ1F + (ib + 1) * 52 + 4 * j4];
            float4 z2 = *(const float4*)&smf[TZ1F + (ib + 2) * 52 + 4 * j4];
            float4 z3 = *(const float4*)&smf[TZ1F + (ib + 3) * 52 + 4 * j4];
            a0 = fmaf(w.x, z0.x, fmaf(w.y, z0.y, fmaf(w.z, z0.z, fmaf(w.w, z0.w, a0))));
            a1 = fmaf(w.x, z1.x, fmaf(w.y, z1.y, fmaf(w.z, z1.z, fmaf(w.w, z1.w, a1))));
            a2 = fmaf(w.x, z2.x, fmaf(w.y, z2.y, fmaf(w.z, z2.z, fmaf(w.w, z2.w, a2))));
            a3 = fmaf(w.x, z3.x, fmaf(w.y, z3.y, fmaf(w.z, z3.z, fmaf(w.w, z3.w, a3))));
        }
        if (lane < 15) {
            smf[TZVF + (ib + 0) * 17 + lane] = a0 * 100.0f;
            smf[TZVF + (ib + 1) * 17 + lane] = a1 * 100.0f;
            smf[TZVF + (ib + 2) * 17 + lane] = a2 * 100.0f;
            smf[TZVF + (ib + 3) * 17 + lane] = a3 * 100.0f;
        }
    }
    __syncthreads();

    if (g == 0 && lane < 16) {
        const float* zv = &smf[TZVF + lane * 17];
        float* ob = out + (size_t)(i0 + lane) * 15;
        #pragma unroll
        for (int c = 9; c < 15; c++) ob[c] = zv[c];

        const float A00 = zv[0], A01 = zv[1], A02 = zv[2];
        const float A10 = zv[3], A11 = zv[4], A12 = zv[5];
        const float A20 = zv[6], A21 = zv[7], A22 = zv[8];
        float S00 = A00*A00 + A10*A10 + A20*A20;
        float S01 = A00*A01 + A10*A11 + A20*A21;
        float S02 = A00*A02 + A10*A12 + A20*A22;
        float S11 = A01*A01 + A11*A11 + A21*A21;
        float S12 = A01*A02 + A11*A12 + A21*A22;
        float S22 = A02*A02 + A12*A12 + A22*A22;
        float V00=1.f, V01=0.f, V02=0.f;
        float V10=0.f, V11=1.f, V12=0.f;
        float V20=0.f, V21=0.f, V22=1.f;
        #pragma unroll
        for (int sweep = 0; sweep < 8; sweep++) {
            JROT(S00, S11, S01, S02, S12, V00, V01, V10, V11, V20, V21)
            JROT(S00, S22, S02, S01, S12, V00, V02, V10, V12, V20, V22)
            JROT(S11, S22, S12, S01, S02, V01, V02, V11, V12, V21, V22)
        }
        float e0 = S00, e1 = S11, e2 = S22;
        float va0=V00, va1=V10, va2=V20;
        float vb0=V01, vb1=V11, vb2=V21;
        float vc0=V02, vc1=V12, vc2=V22;
        float sgn = 1.0f, tq;
        if (e0 < e1) { tq=e0;e0=e1;e1=tq; tq=va0;va0=vb0;vb0=tq; tq=va1;va1=vb1;vb1=tq; tq=va2;va2=vb2;vb2=tq; sgn=-sgn; }
        if (e1 < e2) { tq=e1;e1=e2;e2=tq; tq=vb0;vb0=vc0;vc0=tq; tq=vb1;vb1=vc1;vc1=tq; tq=vb2;vb2=vc2;vc2=tq; sgn=-sgn; }
        if (e0 < e1) { tq=e0;e0=e1;e1=tq; tq=va0;va0=vb0;vb0=tq; tq=va1;va1=vb1;vb1=tq; tq=va2;va2=vb2;vb2=tq; sgn=-sgn; }
        vc0 *= sgn; vc1 *= sgn; vc2 *= sgn;
        float u10 = A00*va0 + A01*va1 + A02*va2;
        float u11 = A10*va0 + A11*va1 + A12*va2;
        float u12 = A20*va0 + A21*va1 + A22*va2;
        float n1 = sqrtf(u10*u10 + u11*u11 + u12*u12);
        float rn1 = (n1 > 1e-20f) ? 1.0f / n1 : 0.0f;
        u10 *= rn1; u11 *= rn1; u12 *= rn1;
        float u20 = A00*vb0 + A01*vb1 + A02*vb2;
        float u21 = A10*vb0 + A11*vb1 + A12*vb2;
        float u22 = A20*vb0 + A21*vb1 + A22*vb2;
        float d12 = u20*u10 + u21*u11 + u22*u12;
        u20 -= d12*u10; u21 -= d12*u11; u22 -= d12*u12;
        float n2 = sqrtf(u20*u20 + u21*u21 + u22*u22);
        float rn2 = (n2 > 1e-20f) ? 1.0f / n2 : 0.0f;
        u20 *= rn2; u21 *= rn2; u22 *= rn2;
        float u30 = u11*u22 - u12*u21;
        float u31 = u12*u20 - u10*u22;
        float u32 = u10*u21 - u11*u20;
        ob[0] = u10*va0 + u20*vb0 + u30*vc0;
        ob[1] = u10*va1 + u20*vb1 + u30*vc1;
        ob[2] = u10*va2 + u20*vb2 + u30*vc2;
        ob[3] = u11*va0 + u21*vb0 + u31*vc0;
        ob[4] = u11*va1 + u21*vb1 + u31*vc1;
        ob[5] = u11*va2 + u21*vb2 + u31*vc2;
        ob[6] = u12*va0 + u22*vb0 + u32*vc0;
        ob[7] = u12*va1 + u22*vb1 + u32*vc1;
        ob[8] = u12*va2 + u22*vb2 + u32*vc2;
    }
}

extern "C" void kernel_launch(void* const* d_in, const int* in_sizes, int n_in,
                              void* d_out, int out_size, void* d_ws, size_t ws_size,
                              hipStream_t stream) {
    (void)n_in; (void)out_size; (void)ws_size;
    const float* x     = (const float*)d_in[0];
    const float* calib = (const float*)d_in[1];
    const float* biasv = (const float*)d_in[2];
    const float* cw1   = (const float*)d_in[3];
    const float* cb1   = (const float*)d_in[4];
    const float* cw2   = (const float*)d_in[5];
    const float* cb2   = (const float*)d_in[6];
    const float* cw3   = (const float*)d_in[7];
    const float* cb3   = (const float*)d_in[8];
    const float* cw4   = (const float*)d_in[9];
    const float* cb4   = (const float*)d_in[10];
    const float* lw1   = (const float*)d_in[11];
    const float* lb1   = (const float*)d_in[12];
    const float* lw2   = (const float*)d_in[13];
    const float* lb2   = (const float*)d_in[14];
    const float* lw3   = (const float*)d_in[15];
    const float* lb3   = (const float*)d_in[16];
    float* out = (float*)d_out;
    ushort_t* wsh = (ushort_t*)d_ws;
    float* Fb = (float*)((char*)d_ws + WS_F_BYTE_OFF);
    const int B = in_sizes[0] / 1400;

    hipLaunchKernelGGL(prep_kernel, dim3(35), dim3(512), 0, stream,
                       cw1, cw2, cw3, cw4, wsh);
    hipLaunchKernelGGL(rminet_conv_kernel, dim3(B), dim3(NTHREADS), 0, stream,
                       x, calib, biasv, cb1, cb2, cb3, cb4,
                       (const ushort_t*)wsh, Fb);
    hipLaunchKernelGGL(rminet_tail_kernel, dim3(B / 16), dim3(256), 0, stream,
                       (const float*)Fb, lw1, lb1, lw2, lb2, lw3, lb3, out);
}